// Round 1
// baseline (575.625 us; speedup 1.0000x reference)
//
#include <hip/hip_runtime.h>
#include <stdint.h>

#define NB 64
#define NS 2048
#define ND 1024
#define NU 1024

typedef __attribute__((ext_vector_type(8))) _Float16 f16x8;
typedef __attribute__((ext_vector_type(4))) float f32x4;

// async global->LDS, 16B per lane; lds base must be wave-uniform (HW: base + lane*16)
__device__ __forceinline__ void gload_lds16(const void* g, void* l) {
    __builtin_amdgcn_global_load_lds(
        (const __attribute__((address_space(1))) unsigned int*)g,
        (__attribute__((address_space(3))) unsigned int*)l, 16, 0, 0);
}

// ---------------- K1: U [d][u] fp32 -> Ut [u][d] f16 ----------------
__global__ void transpose_u(const float* __restrict__ Uk, _Float16* __restrict__ Ut) {
    __shared__ float tile[64][65];
    int d0 = blockIdx.x * 64, u0 = blockIdx.y * 64;
    int tid = threadIdx.x;
    #pragma unroll
    for (int i = 0; i < 16; ++i) {
        int idx = i * 256 + tid;
        int r = idx >> 6, c = idx & 63;
        tile[r][c] = Uk[(size_t)(d0 + r) * NU + (u0 + c)];
    }
    __syncthreads();
    #pragma unroll
    for (int i = 0; i < 16; ++i) {
        int idx = i * 256 + tid;
        int c = idx >> 6, r = idx & 63;
        Ut[(size_t)(u0 + c) * ND + (d0 + r)] = (_Float16)tile[r][c];
    }
}

// ---------------- K2: off[b][u] = s_prev@W + W_bias + U_bias ----------------
__global__ void prep_off(const float* __restrict__ s_prev, const float* __restrict__ Wk,
                         const float* __restrict__ Wb, const float* __restrict__ Ub,
                         float* __restrict__ off) {
    int blk = blockIdx.x;          // 256 blocks: b = blk>>2, utile = blk&3
    int b = blk >> 2, ut = blk & 3;
    int tid = threadIdx.x;
    int u = ut * 256 + tid;
    __shared__ float sp[ND];
    #pragma unroll
    for (int i = tid; i < ND; i += 256) sp[i] = s_prev[(size_t)b * ND + i];
    __syncthreads();
    float acc = 0.f;
    #pragma unroll 8
    for (int d = 0; d < ND; ++d) acc += sp[d] * Wk[(size_t)d * NU + u];
    off[(size_t)b * NU + u] = acc + Wb[u] + Ub[u];
}

// ---------------- K3: fused scores GEMM ----------------
// scores[b][s] += sum_u tanh(off[b][u] + sum_d h[b][s][d]*U[d][u]) * V[u]
// 128x128 tile, BK=32, 4 waves (2x2), each wave 64x64 = 4x4 frags of 16x16x32 f16 MFMA.
__launch_bounds__(256, 2)
__global__ void scores_kernel(const float* __restrict__ h,
                              const _Float16* __restrict__ Ut,   // [NU][ND]
                              const float* __restrict__ off,     // [NB][NU]
                              const float* __restrict__ V,       // [NU]
                              float* __restrict__ scores)        // [NB][NS], pre-zeroed
{
    // XCD-bijective swizzle: keep the 8 u-blocks of one h-slab on one XCD
    int hw = blockIdx.x;
    int chunk = gridDim.x >> 3;                    // 8192/8 = 1024
    int logical = (hw & 7) * chunk + (hw >> 3);
    int ublk = logical & 7;
    int t2 = logical >> 3;
    int sblk = t2 & 15;
    int b = t2 >> 4;
    int s0 = sblk * 128, u0 = ublk * 128;

    __shared__ _Float16 As[128][32];   // h tile, [s][k] f16, 8 KB
    __shared__ _Float16 Bs[128][32];   // U^T tile, [u][k] f16, 8 KB

    int tid = threadIdx.x;
    int w = tid >> 6, l = tid & 63;
    int wr = w >> 1, wc = w & 1;
    int rg = l >> 4, cl = l & 15;

    f32x4 acc[4][4] = {};

    const float* hA = h + ((size_t)b * NS + s0) * ND;
    const _Float16* uB = Ut + (size_t)u0 * ND;

    int arow = tid >> 3;          // 0..31 per pass (4 passes of 32 rows)
    int acol = (tid & 7) * 4;     // float4 within the 32-wide K chunk

    for (int kk = 0; kk < 32; ++kk) {
        int k0 = kk * 32;
        // A: global fp32 -> regs (issued before barrier, no LDS touched)
        float4 av[4];
        #pragma unroll
        for (int p = 0; p < 4; ++p)
            av[p] = *(const float4*)(hA + (size_t)(p * 32 + arow) * ND + k0 + acol);

        __syncthreads();   // previous step's compute done -> safe to overwrite LDS

        // B: async global->LDS (already f16, [u][k] rows of 64B)
        #pragma unroll
        for (int i = 0; i < 2; ++i) {
            const _Float16* src = uB + (size_t)(w * 32 + i * 16 + (l >> 2)) * ND + k0 + (l & 3) * 8;
            gload_lds16((const void*)src, (void*)&Bs[w * 32 + i * 16][0]);
        }
        // A: cvt f32->f16, write to LDS
        #pragma unroll
        for (int p = 0; p < 4; ++p) {
            union { _Float16 h4[4]; uint2 u2; } cv;
            cv.h4[0] = (_Float16)av[p].x; cv.h4[1] = (_Float16)av[p].y;
            cv.h4[2] = (_Float16)av[p].z; cv.h4[3] = (_Float16)av[p].w;
            *(uint2*)&As[p * 32 + arow][acol] = cv.u2;
        }

        __syncthreads();   // staging visible (compiler drains vmcnt before s_barrier)

        f16x8 af[4], bf[4];
        #pragma unroll
        for (int m = 0; m < 4; ++m) af[m] = *(const f16x8*)&As[wr * 64 + m * 16 + cl][rg * 8];
        #pragma unroll
        for (int n = 0; n < 4; ++n) bf[n] = *(const f16x8*)&Bs[wc * 64 + n * 16 + cl][rg * 8];
        #pragma unroll
        for (int m = 0; m < 4; ++m)
            #pragma unroll
            for (int n = 0; n < 4; ++n)
                acc[m][n] = __builtin_amdgcn_mfma_f32_16x16x32_f16(af[m], bf[n], acc[m][n], 0, 0, 0);
    }

    // epilogue: tanh(acc + off)*V, reduce over this wave's 64 u's, atomic into scores
    float offv[4], vv[4];
    #pragma unroll
    for (int n = 0; n < 4; ++n) {
        int u = u0 + wc * 64 + n * 16 + cl;
        offv[n] = off[(size_t)b * NU + u];
        vv[n] = V[u];
    }
    #pragma unroll
    for (int m = 0; m < 4; ++m) {
        #pragma unroll
        for (int i = 0; i < 4; ++i) {
            float sacc = 0.f;
            #pragma unroll
            for (int n = 0; n < 4; ++n) {
                float x = acc[m][n][i] + offv[n];
                float t = 1.0f - 2.0f / (1.0f + __expf(2.0f * x));  // tanh(x)
                sacc += t * vv[n];
            }
            #pragma unroll
            for (int msk = 1; msk < 16; msk <<= 1) sacc += __shfl_xor(sacc, msk, 64);
            if (cl == 0)
                atomicAdd(&scores[(size_t)b * NS + s0 + wr * 64 + m * 16 + rg * 4 + i], sacc);
        }
    }
}

// ---------------- K4: softmax over S per batch ----------------
__global__ void softmax_kernel(const float* __restrict__ scores, float* __restrict__ outw) {
    int b = blockIdx.x, tid = threadIdx.x;
    const float* src = scores + (size_t)b * NS;
    float4 x0 = *(const float4*)(src + tid * 8);
    float4 x1 = *(const float4*)(src + tid * 8 + 4);
    float m = fmaxf(fmaxf(fmaxf(x0.x, x0.y), fmaxf(x0.z, x0.w)),
                    fmaxf(fmaxf(x1.x, x1.y), fmaxf(x1.z, x1.w)));
    #pragma unroll
    for (int msk = 1; msk < 64; msk <<= 1) m = fmaxf(m, __shfl_xor(m, msk, 64));
    __shared__ float redm[4], reds[4];
    if ((tid & 63) == 0) redm[tid >> 6] = m;
    __syncthreads();
    m = fmaxf(fmaxf(redm[0], redm[1]), fmaxf(redm[2], redm[3]));
    float e[8];
    e[0] = __expf(x0.x - m); e[1] = __expf(x0.y - m); e[2] = __expf(x0.z - m); e[3] = __expf(x0.w - m);
    e[4] = __expf(x1.x - m); e[5] = __expf(x1.y - m); e[6] = __expf(x1.z - m); e[7] = __expf(x1.w - m);
    float s = e[0] + e[1] + e[2] + e[3] + e[4] + e[5] + e[6] + e[7];
    #pragma unroll
    for (int msk = 1; msk < 64; msk <<= 1) s += __shfl_xor(s, msk, 64);
    if ((tid & 63) == 0) reds[tid >> 6] = s;
    __syncthreads();
    float Z = reds[0] + reds[1] + reds[2] + reds[3];
    float r = 1.0f / Z;
    float4 o0 = { e[0] * r, e[1] * r, e[2] * r, e[3] * r };
    float4 o1 = { e[4] * r, e[5] * r, e[6] * r, e[7] * r };
    *(float4*)(outw + (size_t)b * NS + tid * 8) = o0;
    *(float4*)(outw + (size_t)b * NS + tid * 8 + 4) = o1;
}

// ---------------- K5: context partials over s-chunks ----------------
__global__ void context_partial(const float* __restrict__ h, const float* __restrict__ wgt,
                                float* __restrict__ part) {
    int sc = blockIdx.x, b = blockIdx.y, tid = threadIdx.x;   // 16 chunks x 128 s
    __shared__ float lw[128];
    if (tid < 128) lw[tid] = wgt[(size_t)b * NS + sc * 128 + tid];
    __syncthreads();
    const float* hb = h + ((size_t)b * NS + sc * 128) * ND + tid * 4;
    float4 acc = { 0.f, 0.f, 0.f, 0.f };
    #pragma unroll 4
    for (int s = 0; s < 128; ++s) {
        float4 hv = *(const float4*)(hb + (size_t)s * ND);
        float wv = lw[s];
        acc.x += hv.x * wv; acc.y += hv.y * wv; acc.z += hv.z * wv; acc.w += hv.w * wv;
    }
    *(float4*)(part + ((size_t)(sc * NB + b)) * ND + tid * 4) = acc;
}

// ---------------- K6: reduce partials -> context ----------------
__global__ void context_reduce(const float* __restrict__ part, float* __restrict__ outc) {
    int b = blockIdx.x, tid = threadIdx.x;
    float4 acc = { 0.f, 0.f, 0.f, 0.f };
    #pragma unroll
    for (int k = 0; k < 16; ++k) {
        float4 p = *(const float4*)(part + ((size_t)(k * NB + b)) * ND + tid * 4);
        acc.x += p.x; acc.y += p.y; acc.z += p.z; acc.w += p.w;
    }
    *(float4*)(outc + (size_t)b * ND + tid * 4) = acc;
}

extern "C" void kernel_launch(void* const* d_in, const int* in_sizes, int n_in,
                              void* d_out, int out_size, void* d_ws, size_t ws_size,
                              hipStream_t stream) {
    const float* s_prev = (const float*)d_in[0];
    const float* hidden = (const float*)d_in[1];
    const float* Wk     = (const float*)d_in[2];
    const float* Wb     = (const float*)d_in[3];
    const float* Uk     = (const float*)d_in[4];
    const float* Ub     = (const float*)d_in[5];
    const float* Vk     = (const float*)d_in[6];
    // V_bias (d_in[7]) is a uniform score shift -> softmax-invariant, dropped.

    float* out_ctx = (float*)d_out;            // [64][1024]
    float* out_w   = out_ctx + NB * ND;        // [64][2048]

    char* ws = (char*)d_ws;
    _Float16* Ut  = (_Float16*)ws;                                   // 2 MB
    float* off    = (float*)(ws + (size_t)(2 << 20));                // 256 KB
    float* scores = (float*)(ws + (size_t)(2 << 20) + (256 << 10));  // 512 KB
    float* part   = (float*)(ws + (size_t)(2 << 20) + (768 << 10));  // 4 MB

    hipMemsetAsync(scores, 0, (size_t)NB * NS * sizeof(float), stream);
    transpose_u<<<dim3(16, 16), 256, 0, stream>>>(Uk, Ut);
    prep_off<<<256, 256, 0, stream>>>(s_prev, Wk, Wb, Ub, off);
    scores_kernel<<<8192, 256, 0, stream>>>(hidden, Ut, off, Vk, scores);
    softmax_kernel<<<NB, 256, 0, stream>>>(scores, out_w);
    context_partial<<<dim3(16, NB), 256, 0, stream>>>(hidden, out_w, part);
    context_reduce<<<NB, 256, 0, stream>>>(part, out_ctx);
}